// Round 12
// baseline (47.915 us; speedup 1.0000x reference)
//
#include <hip/hip_runtime.h>

// Volume rendering: R=65536 rays, N=128 sorted samples/ray. fp32 in/out.
// HARD-WON RULES (rounds 2-11):
//  (1) __shfl_* is broken here (error signature = 32-wide halves; identical
//      math via LDS passes) — ALL cross-lane via LDS.
//  (2) Input order IS dict order (r7 detect == r3 no-detect bit-identical;
//      r8-r11 pass with dict order).
//  (3) fp32 in, fp32 out, out = feat[R,3] then depth[R].
//  (4) r11 lesson: barriers are NOT the limiter; don't trade occupancy
//      (LDS/VGPR) for per-thread MLP.
//
// r12: r10 inner body verbatim + grid-stride (2048 blocks, statically
// resident, 32 rays/block over 8 iterations) + register double-buffered
// prefetch of the next iteration's 13 loads — hides HBM latency under the
// current iteration's LDS scan/reduction phases. Discriminates
// latency-bound (H1) vs load-path-ceiling (H2).

#define R_RAYS 65536
#define N_SAMP 128
#define FAR_DELTA 1e10f
#define NBLOCKS 2048
#define RAYS_PER_BLOCK (R_RAYS / NBLOCKS)   // 32
#define ITERS (RAYS_PER_BLOCK / 4)          // 8 (4 waves/block, 1 ray/wave/iter)

struct RayRegs {
    float d0, d1, d2v, g0, g1;
    float f0, f1, f2, f3, f4, f5;
    float p2, p5;
};

__device__ __forceinline__ RayRegs load_ray(
    const float* __restrict__ dv, const float* __restrict__ dn,
    const float* __restrict__ ft, const float* __restrict__ sp,
    int ray, int lane)
{
    RayRegs r;
    const size_t base = (size_t)ray * N_SAMP + (size_t)(lane * 2);
    const size_t b3   = base * 3;
    r.d0  = dv[base];
    r.d1  = dv[base + 1];
    r.d2v = (lane == 63) ? 0.0f : dv[base + 2];
    r.g0  = dn[base];
    r.g1  = dn[base + 1];
    r.f0  = ft[b3 + 0];
    r.f1  = ft[b3 + 1];
    r.f2  = ft[b3 + 2];
    r.f3  = ft[b3 + 3];
    r.f4  = ft[b3 + 4];
    r.f5  = ft[b3 + 5];
    r.p2  = sp[b3 + 2];
    r.p5  = sp[b3 + 5];
    return r;
}

__global__ __launch_bounds__(256) void volrend_kernel(
    const float* __restrict__ dv,   // depth_values [R,N]
    const float* __restrict__ dn,   // density      [R,N]
    const float* __restrict__ ft,   // feature      [R,N,3]
    const float* __restrict__ sp,   // sample_points[R,N,3]
    float* __restrict__ out_feat,   // [R,3]
    float* __restrict__ out_depth)  // [R]
{
    __shared__ float  s_scan[4][64];   // per-wave pair-sums of sig_delta
    __shared__ float  s_gsum[4][8];    // group totals (groups of 8)
    __shared__ float4 s_red [4][64];   // (fx,fy,fz,dp) partials
    __shared__ float4 s_red8[4][8];    // group partials

    const int w    = threadIdx.x >> 6;   // wave in block (0..3)
    const int lane = threadIdx.x & 63;
    const int g    = lane >> 3;          // group 0..7
    const int gl   = lane & 7;           // pos in group
    const int ray_base = blockIdx.x * RAYS_PER_BLOCK + w;

    // prefetch iteration 0
    RayRegs cur = load_ray(dv, dn, ft, sp, ray_base, lane);

    #pragma unroll
    for (int it = 0; it < ITERS; ++it) {
        const int ray = ray_base + it * 4;

        // ---- issue next iteration's 13 loads NOW (hide under LDS phases) ----
        RayRegs nxt;
        if (it + 1 < ITERS)
            nxt = load_ray(dv, dn, ft, sp, ray_base + (it + 1) * 4, lane);

        // ---- sig_delta ----
        float delta0 = cur.d1 - cur.d0;
        float delta1 = (lane == 63) ? FAR_DELTA : (cur.d2v - cur.d1);
        float s0 = -cur.g0 * delta0;
        float s1 = -cur.g1 * delta1;
        float lsum = s0 + s1;

        // ---- hierarchical exclusive scan (groups of 8), via LDS ----
        s_scan[w][lane] = lsum;
        __syncthreads();

        float excl_g = 0.0f;
        #pragma unroll
        for (int k = 0; k < 7; ++k) {
            float v = s_scan[w][(g << 3) + k];
            if (k < gl) excl_g += v;
        }
        if (gl == 7) s_gsum[w][g] = excl_g + lsum;
        __syncthreads();

        float gexcl = 0.0f;
        #pragma unroll
        for (int j = 0; j < 7; ++j) {
            float v = s_gsum[w][j];
            if (j < g) gexcl += v;
        }
        float excl0 = gexcl + excl_g;   // sum sig_delta[0..2l-1]
        float excl1 = excl0 + s0;       // sum sig_delta[0..2l]

        // weights = trans * (1 - exp(sig_delta)); exp(-sig*1e10) underflows to 0
        float w0 = __expf(excl0) * (1.0f - __expf(s0));
        float w1 = __expf(excl1) * (1.0f - __expf(s1));

        float fx = w0 * cur.f0 + w1 * cur.f3;
        float fy = w0 * cur.f1 + w1 * cur.f4;
        float fz = w0 * cur.f2 + w1 * cur.f5;
        float dp = cur.g0 * cur.p2 + cur.g1 * cur.p5;

        // ---- 2-barrier group-of-8 reduction ----
        s_red[w][lane] = make_float4(fx, fy, fz, dp);
        __syncthreads();
        if (gl == 0) {
            float4 acc = make_float4(0.f, 0.f, 0.f, 0.f);
            #pragma unroll
            for (int k = 0; k < 8; ++k) {
                int idx = (g << 3) + ((k + g) & 7);   // stagger banks
                float4 t = s_red[w][idx];
                acc.x += t.x; acc.y += t.y; acc.z += t.z; acc.w += t.w;
            }
            s_red8[w][g] = acc;
        }
        __syncthreads();

        if (lane == 0) {
            float4 acc = s_red8[w][0];
            #pragma unroll
            for (int k = 1; k < 8; ++k) {
                float4 t = s_red8[w][k];
                acc.x += t.x; acc.y += t.y; acc.z += t.z; acc.w += t.w;
            }
            out_feat[(size_t)ray * 3 + 0] = acc.x;
            out_feat[(size_t)ray * 3 + 1] = acc.y;
            out_feat[(size_t)ray * 3 + 2] = acc.z;
            out_depth[ray] = acc.w * (1.0f / N_SAMP);
        }

        cur = nxt;
    }
}

extern "C" void kernel_launch(void* const* d_in, const int* in_sizes, int n_in,
                              void* d_out, int out_size, void* d_ws, size_t ws_size,
                              hipStream_t stream) {
    const float* depth_values  = (const float*)d_in[0];
    const float* density       = (const float*)d_in[1];
    const float* feature       = (const float*)d_in[2];
    const float* sample_points = (const float*)d_in[3];

    float* out_feat  = (float*)d_out;                       // [R,3] first
    float* out_depth = (float*)d_out + (size_t)R_RAYS * 3;  // [R] after

    dim3 grid(NBLOCKS);   // 8 blocks/CU statically resident, 32 rays/block
    volrend_kernel<<<grid, 256, 0, stream>>>(
        depth_values, density, feature, sample_points, out_feat, out_depth);
}

// Round 13
// 43.636 us; speedup vs baseline: 1.0981x; 1.0981x over previous
//
#include <hip/hip_runtime.h>

// Volume rendering: R=65536 rays, N=128 sorted samples/ray. fp32 in/out.
// HARD-WON RULES (rounds 2-12):
//  (1) __shfl_* is broken for 64-lane semantics here (three bit-identical
//      failures; identical math via LDS passes) — ALL cross-lane via LDS.
//  (2) Input order IS dict order (r7 detect == r3 no-detect bit-identical;
//      r11/r12 pass with hardcoded dict order). Detection removed.
//  (3) fp32 in, fp32 out, out = feat[R,3] then depth[R].
//  (4) r11/r12 lessons: NOT latency-bound — extra MLP (2 rays/wave, register
//      prefetch, resident blocks) costs occupancy and regresses. Aggregate
//      ingest is pinned at ~6.2 TB/s = m13 ceiling; r10's balance is optimal.
//
// r13 = r10 structure (best: 43.25 us) minus the vestigial detection phase.
// One wave per ray; lane l owns samples 2l, 2l+1. 4 barriers/block.

#define R_RAYS 65536
#define N_SAMP 128
#define FAR_DELTA 1e10f

__global__ __launch_bounds__(256) void volrend_kernel(
    const float* __restrict__ dv,   // depth_values [R,N]
    const float* __restrict__ dn,   // density      [R,N]
    const float* __restrict__ ft,   // feature      [R,N,3]
    const float* __restrict__ sp,   // sample_points[R,N,3]
    float* __restrict__ out_feat,   // [R,3]
    float* __restrict__ out_depth)  // [R]
{
    __shared__ float  s_scan[4][64];   // per-wave pair-sums of sig_delta
    __shared__ float  s_gsum[4][8];    // group totals (groups of 8)
    __shared__ float4 s_red [4][64];   // (fx,fy,fz,dp) partials
    __shared__ float4 s_red8[4][8];    // group partials

    const int w    = threadIdx.x >> 6;          // wave in block (0..3)
    const int lane = threadIdx.x & 63;
    const int g    = lane >> 3;                 // group 0..7
    const int gl   = lane & 7;                  // pos in group
    const int ray  = (blockIdx.x << 2) + w;     // grid sized exactly: ray < R

    const size_t base = (size_t)ray * N_SAMP + (size_t)(lane * 2);  // sample 2l
    const size_t b3   = base * 3;

    // ---- issue ALL global loads up front (latency hides under scan) ----
    float d0  = dv[base];
    float d1  = dv[base + 1];
    float d2v = (lane == 63) ? 0.0f : dv[base + 2];
    float g0  = dn[base];
    float g1  = dn[base + 1];
    float f0  = ft[b3 + 0];
    float f1  = ft[b3 + 1];
    float f2  = ft[b3 + 2];
    float f3  = ft[b3 + 3];
    float f4  = ft[b3 + 4];
    float f5  = ft[b3 + 5];
    float p2  = sp[b3 + 2];
    float p5  = sp[b3 + 5];

    float delta0 = d1 - d0;
    float delta1 = (lane == 63) ? FAR_DELTA : (d2v - d1);

    float s0 = -g0 * delta0;   // sig_delta[2l]
    float s1 = -g1 * delta1;   // sig_delta[2l+1]
    float lsum = s0 + s1;

    // ---- hierarchical exclusive scan of pair sums (groups of 8) ----
    s_scan[w][lane] = lsum;
    __syncthreads();

    float excl_g = 0.0f;        // within-group exclusive prefix
    #pragma unroll
    for (int k = 0; k < 7; ++k) {
        float v = s_scan[w][(g << 3) + k];
        if (k < gl) excl_g += v;
    }
    if (gl == 7) s_gsum[w][g] = excl_g + lsum;   // inclusive group total
    __syncthreads();

    float gexcl = 0.0f;         // sum of full groups before g
    #pragma unroll
    for (int j = 0; j < 7; ++j) {
        float v = s_gsum[w][j];              // broadcast
        if (j < g) gexcl += v;
    }
    float excl0 = gexcl + excl_g;   // sum sig_delta[0 .. 2l-1]
    float excl1 = excl0 + s0;       // sum sig_delta[0 .. 2l]

    // weights = trans * (1 - exp(sig_delta)); exp(-sigma*1e10) underflows to 0
    float w0 = __expf(excl0) * (1.0f - __expf(s0));
    float w1 = __expf(excl1) * (1.0f - __expf(s1));

    float fx = w0 * f0 + w1 * f3;
    float fy = w0 * f1 + w1 * f4;
    float fz = w0 * f2 + w1 * f5;
    float dp = g0 * p2 + g1 * p5;

    // ---- 2-barrier group-of-8 reduction ----
    s_red[w][lane] = make_float4(fx, fy, fz, dp);
    __syncthreads();
    if (gl == 0) {
        float4 acc = make_float4(0.f, 0.f, 0.f, 0.f);
        #pragma unroll
        for (int k = 0; k < 8; ++k) {
            int idx = (g << 3) + ((k + g) & 7);   // stagger: no same-bank pileup
            float4 t = s_red[w][idx];
            acc.x += t.x; acc.y += t.y; acc.z += t.z; acc.w += t.w;
        }
        s_red8[w][g] = acc;
    }
    __syncthreads();

    if (lane == 0) {
        float4 acc = s_red8[w][0];
        #pragma unroll
        for (int k = 1; k < 8; ++k) {
            float4 t = s_red8[w][k];
            acc.x += t.x; acc.y += t.y; acc.z += t.z; acc.w += t.w;
        }
        out_feat[(size_t)ray * 3 + 0] = acc.x;
        out_feat[(size_t)ray * 3 + 1] = acc.y;
        out_feat[(size_t)ray * 3 + 2] = acc.z;
        out_depth[ray] = acc.w * (1.0f / N_SAMP);
    }
}

extern "C" void kernel_launch(void* const* d_in, const int* in_sizes, int n_in,
                              void* d_out, int out_size, void* d_ws, size_t ws_size,
                              hipStream_t stream) {
    const float* depth_values  = (const float*)d_in[0];
    const float* density       = (const float*)d_in[1];
    const float* feature       = (const float*)d_in[2];
    const float* sample_points = (const float*)d_in[3];

    float* out_feat  = (float*)d_out;                       // [R,3] first
    float* out_depth = (float*)d_out + (size_t)R_RAYS * 3;  // [R] after

    dim3 grid(R_RAYS / 4);   // 4 rays (waves) per 256-thread block
    volrend_kernel<<<grid, 256, 0, stream>>>(
        depth_values, density, feature, sample_points, out_feat, out_depth);
}